// Round 7
// baseline (283.967 us; speedup 1.0000x reference)
//
#include <hip/hip_runtime.h>

#define N_NODES 50000
#define N_EDGES 800000
#define DIN 256
#define DHID 128
#define DOUT 64
#define NB_SCAN 49   // ceil(50000/1024)
#define SENT N_NODES // sentinel node with zero feature row

typedef __attribute__((ext_vector_type(8))) short short8;
typedef __attribute__((ext_vector_type(4))) float f32x4;

static __device__ __forceinline__ short f2bf(float f) {
    union { float f; unsigned u; } v; v.f = f;
    unsigned r = v.u + 0x7FFFu + ((v.u >> 16) & 1u);   // RNE
    return (short)(r >> 16);
}
static __device__ __forceinline__ float bflo(unsigned p) {
    union { unsigned u; float f; } v; v.u = p << 16; return v.f;
}
static __device__ __forceinline__ float bfhi(unsigned p) {
    union { unsigned u; float f; } v; v.u = p & 0xFFFF0000u; return v.f;
}

// ---------------- CSR build (rows padded to multiple of 8 with SENT) ----------------

__global__ void count_kernel(const int* __restrict__ ei, int* __restrict__ cnt,
                             int* __restrict__ loc) {
    int stride = gridDim.x * blockDim.x;
    for (int e = blockIdx.x * blockDim.x + threadIdx.x; e < N_EDGES; e += stride) {
        loc[e] = atomicAdd(&cnt[ei[N_EDGES + e]], 1);
    }
}

__global__ __launch_bounds__(1024) void bsum_kernel(const int* __restrict__ cnt,
                                                    int* __restrict__ bsum) {
    __shared__ int ws[16];
    int tid = threadIdx.x, i = blockIdx.x * 1024 + tid;
    int v = (i < N_NODES) ? cnt[i] : 0;
    v = (v + 7) & ~7;   // padded length
    #pragma unroll
    for (int off = 32; off >= 1; off >>= 1) v += __shfl_xor(v, off);
    if ((tid & 63) == 0) ws[tid >> 6] = v;
    __syncthreads();
    if (tid == 0) {
        int s = 0;
        #pragma unroll
        for (int w = 0; w < 16; ++w) s += ws[w];
        bsum[blockIdx.x] = s;
    }
}

__global__ void bscan_kernel(const int* __restrict__ bsum, int* __restrict__ bo,
                             int* __restrict__ rowptr) {
    int l = threadIdx.x;   // 64 threads
    int v = (l < NB_SCAN) ? bsum[l] : 0;
    int x = v;
    #pragma unroll
    for (int off = 1; off < 64; off <<= 1) {
        int y = __shfl_up(x, off);
        if (l >= off) x += y;
    }
    if (l < NB_SCAN) bo[l] = x - v;
    if (l == 63) rowptr[N_NODES] = x;
}

__global__ __launch_bounds__(1024) void scan_apply_kernel(const int* __restrict__ cnt,
        const int* __restrict__ bo, int* __restrict__ rowptr,
        float* __restrict__ dis, int* __restrict__ col) {
    __shared__ int wsum[16];
    int tid = threadIdx.x, i = blockIdx.x * 1024 + tid;
    int lane = tid & 63, wid = tid >> 6;
    int v = (i < N_NODES) ? cnt[i] : 0;
    int p = (v + 7) & ~7;
    int x = p;
    #pragma unroll
    for (int off = 1; off < 64; off <<= 1) {
        int y = __shfl_up(x, off);
        if (lane >= off) x += y;
    }
    if (lane == 63) wsum[wid] = x;
    __syncthreads();
    if (tid == 0) {
        int s = 0;
        #pragma unroll
        for (int w = 0; w < 16; ++w) { int t = wsum[w]; wsum[w] = s; s += t; }
    }
    __syncthreads();
    int excl = bo[blockIdx.x] + wsum[wid] + (x - p);
    if (i < N_NODES) {
        rowptr[i] = excl;
        dis[i] = rsqrtf((float)(v + 1));
        for (int q = v; q < p; ++q) col[excl + q] = SENT;   // pad slots -> zero row
    }
}

// Atomic-free placement.
__global__ void fill_kernel(const int* __restrict__ ei, const int* __restrict__ loc,
                            const int* __restrict__ rowptr, int* __restrict__ col) {
    int stride = gridDim.x * blockDim.x;
    for (int e = blockIdx.x * blockDim.x + threadIdx.x; e < N_EDGES; e += stride) {
        int s = ei[e];
        int d = ei[N_EDGES + e];
        col[rowptr[d] + loc[e]] = s;
    }
}

// ---------------- weight prep ----------------

__global__ void wprep_kernel(const float* __restrict__ W1, const float* __restrict__ Wmu,
                             const float* __restrict__ Wlv, short* __restrict__ W1b,
                             short* __restrict__ Wctb) {
    int tid = blockIdx.x * blockDim.x + threadIdx.x;
    if (tid < DHID * DIN) {
        W1b[tid] = f2bf(W1[tid]);
    } else if (tid < DHID * DIN + 2 * DOUT * DHID) {
        int t = tid - DHID * DIN;
        Wctb[t] = f2bf((t < DOUT * DHID) ? Wmu[t] : Wlv[t - DOUT * DHID]);
    }
}

// ---------------- xprep: xb[n][k] = bf16(dis[n] * x[n][k]) ----------------
// Streaming, fully coalesced: 8 elems/thread (2 float4 in, 1 short8 out).

__global__ __launch_bounds__(256) void xprep_kernel(const float* __restrict__ x,
        const float* __restrict__ dis, short* __restrict__ xb) {
    const int total = N_NODES * (DIN / 8);
    int stride = gridDim.x * blockDim.x;
    for (int c = blockIdx.x * blockDim.x + threadIdx.x; c < total; c += stride) {
        int row = c >> 5;            // DIN/8 = 32 chunks per row
        float d = dis[row];
        const float* src = x + (size_t)c * 8;
        float4 f0 = *(const float4*)src;
        float4 f1 = *(const float4*)(src + 4);
        short8 o;
        o[0] = f2bf(f0.x * d); o[1] = f2bf(f0.y * d);
        o[2] = f2bf(f0.z * d); o[3] = f2bf(f0.w * d);
        o[4] = f2bf(f1.x * d); o[5] = f2bf(f1.y * d);
        o[6] = f2bf(f1.z * d); o[7] = f2bf(f1.w * d);
        *(short8*)(xb + (size_t)c * 8) = o;
    }
}

// ---------------- GEMM1 (MFMA bf16): u1b = bf16(xb @ W1^T) ----------------
// Wave: 16 rows x 64 cols (4 c-frags); block: 4 waves = 32 rows x 128 cols.
// A-loads feed MFMA directly (no VALU between) -> compiler pipelines on vmcnt.

__global__ __launch_bounds__(256) void gemm1_mfma_kernel(const short* __restrict__ xb,
        const short* __restrict__ W1b, short* __restrict__ u1b) {
    const int lane = threadIdx.x & 63, w = threadIdx.x >> 6;
    const int l15 = lane & 15, kg = lane >> 4;
    const int rowg = w >> 1, colh = w & 1;
    const int nb = blockIdx.x * 32 + rowg * 16;
    const int r0 = nb + l15;
    const bool valid = r0 < N_NODES;
    const short* arow = xb + (size_t)r0 * DIN;

    f32x4 acc[4] = {};
    #pragma unroll
    for (int ks = 0; ks < 8; ++ks) {
        const int k0 = ks * 32 + kg * 8;
        short8 a = valid ? *(const short8*)(arow + k0)
                         : short8{0, 0, 0, 0, 0, 0, 0, 0};
        #pragma unroll
        for (int c = 0; c < 4; ++c) {
            const int cc = colh * 4 + c;
            short8 b = *(const short8*)(W1b + (size_t)(cc * 16 + l15) * DIN + k0);
            acc[c] = __builtin_amdgcn_mfma_f32_16x16x32_bf16(a, b, acc[c], 0, 0, 0);
        }
    }

    const int rb = nb + kg * 4;
    #pragma unroll
    for (int c = 0; c < 4; ++c) {
        const int j = (colh * 4 + c) * 16 + l15;
        #pragma unroll
        for (int e = 0; e < 4; ++e) {
            int r = rb + e;
            if (r < N_NODES)
                u1b[(size_t)r * DHID + j] = f2bf(acc[c][e]);
        }
    }
}

// ---------------- pull aggregation (one wave per node; padded rows, x8 gathers) ----------------

template <bool LAYER1>
__global__ __launch_bounds__(256) void pull_kernel(const int* __restrict__ rowptr,
        const int* __restrict__ col, const short* __restrict__ uin,
        const float* __restrict__ dis, const float* __restrict__ b1,
        unsigned* __restrict__ uout) {
    const int wid = threadIdx.x >> 6, lane = threadIdx.x & 63;
    const int i = blockIdx.x * 4 + wid;
    if (i >= N_NODES) return;
    const int beg = rowptr[i], end = rowptr[i + 1];
    const unsigned* __restrict__ up = (const unsigned*)uin;   // row stride 64 dwords
    float ax = 0.f, ay = 0.f;
    for (int base = beg; base < end; base += 64) {
        const int rem = end - base;
        const int m = rem < 64 ? rem : 64;          // multiple of 8
        int cv = (lane < m) ? col[base + lane] : SENT;
        for (int t = 0; t < m; t += 8) {
            int c0 = __shfl(cv, t);
            int c1 = __shfl(cv, t + 1);
            int c2 = __shfl(cv, t + 2);
            int c3 = __shfl(cv, t + 3);
            int c4 = __shfl(cv, t + 4);
            int c5 = __shfl(cv, t + 5);
            int c6 = __shfl(cv, t + 6);
            int c7 = __shfl(cv, t + 7);
            unsigned v0 = up[(size_t)c0 * 64 + lane];
            unsigned v1 = up[(size_t)c1 * 64 + lane];
            unsigned v2 = up[(size_t)c2 * 64 + lane];
            unsigned v3 = up[(size_t)c3 * 64 + lane];
            unsigned v4 = up[(size_t)c4 * 64 + lane];
            unsigned v5 = up[(size_t)c5 * 64 + lane];
            unsigned v6 = up[(size_t)c6 * 64 + lane];
            unsigned v7 = up[(size_t)c7 * 64 + lane];
            ax += bflo(v0); ay += bfhi(v0);
            ax += bflo(v1); ay += bfhi(v1);
            ax += bflo(v2); ay += bfhi(v2);
            ax += bflo(v3); ay += bfhi(v3);
            ax += bflo(v4); ay += bfhi(v4);
            ax += bflo(v5); ay += bfhi(v5);
            ax += bflo(v6); ay += bfhi(v6);
            ax += bflo(v7); ay += bfhi(v7);
        }
    }
    const float di = dis[i];
    const unsigned sv = up[(size_t)i * 64 + lane];
    float tx = di * (ax + bflo(sv));
    float ty = di * (ay + bfhi(sv));
    if (LAYER1) {
        float2 b = *(const float2*)(b1 + lane * 2);
        tx = fmaxf(tx + b.x, 0.f) * di;
        ty = fmaxf(ty + b.y, 0.f) * di;
    }
    unsigned o = ((unsigned)(unsigned short)f2bf(tx)) |
                 (((unsigned)(unsigned short)f2bf(ty)) << 16);
    uout[(size_t)i * 64 + lane] = o;
}

// ---------------- GEMM2 (MFMA bf16): [mu|lv] = a2b @ Wctb^T + [bmu|blv] ----------------

__global__ __launch_bounds__(256) void gemm2_mfma_kernel(const short* __restrict__ a2b,
        const short* __restrict__ Wctb, const float* __restrict__ bmu,
        const float* __restrict__ blv, float* __restrict__ out) {
    const int lane = threadIdx.x & 63, w = threadIdx.x >> 6;
    const int l15 = lane & 15, kg = lane >> 4;
    const int nb = blockIdx.x * 64;
    const int r0 = nb + w * 16 + l15;
    const bool valid = r0 < N_NODES;
    const short* arow = a2b + (size_t)r0 * DHID;

    f32x4 acc[8] = {};
    #pragma unroll
    for (int ks = 0; ks < 4; ++ks) {
        const int k0 = ks * 32 + kg * 8;
        short8 a = valid ? *(const short8*)(arow + k0)
                         : short8{0, 0, 0, 0, 0, 0, 0, 0};
        #pragma unroll
        for (int c = 0; c < 8; ++c) {
            short8 b = *(const short8*)(Wctb + (size_t)(c * 16 + l15) * DHID + k0);
            acc[c] = __builtin_amdgcn_mfma_f32_16x16x32_bf16(a, b, acc[c], 0, 0, 0);
        }
    }

    float bias[8];
    #pragma unroll
    for (int c = 0; c < 8; ++c) {
        int j = c * 16 + l15;
        bias[c] = (j < DOUT) ? bmu[j] : blv[j - DOUT];
    }
    const int rb = nb + w * 16 + kg * 4;
    #pragma unroll
    for (int c = 0; c < 8; ++c) {
        const int j = c * 16 + l15;
        float* dst = (j < DOUT) ? (out + j)
                                : (out + (size_t)N_NODES * DOUT + (j - DOUT));
        #pragma unroll
        for (int e = 0; e < 4; ++e) {
            int r = rb + e;
            if (r < N_NODES)
                dst[(size_t)r * DOUT] = acc[c][e] + bias[c];
        }
    }
}

// ---------------- launcher ----------------

extern "C" void kernel_launch(void* const* d_in, const int* in_sizes, int n_in,
                              void* d_out, int out_size, void* d_ws, size_t ws_size,
                              hipStream_t stream) {
    const float* x   = (const float*)d_in[0];
    const int*   ei  = (const int*)d_in[1];
    const float* W1  = (const float*)d_in[2];
    const float* b1  = (const float*)d_in[3];
    const float* Wmu = (const float*)d_in[4];
    const float* bmu = (const float*)d_in[5];
    const float* Wlv = (const float*)d_in[6];
    const float* blv = (const float*)d_in[7];
    float* out = (float*)d_out;

    char* ws = (char*)d_ws;
    size_t off = 0;
    auto alloc = [&](size_t bytes) -> char* {
        char* p = ws + off;
        off += (bytes + 255) & ~(size_t)255;
        return p;
    };
    const size_t COL_CAP = (size_t)N_EDGES + 8 * (size_t)N_NODES + 64;  // padded CSR
    int*   cnt    = (int*)  alloc((size_t)N_NODES * 4);
    int*   rowptr = (int*)  alloc((size_t)(N_NODES + 1) * 4);
    float* dis    = (float*)alloc((size_t)N_NODES * 4);
    int*   loc    = (int*)  alloc((size_t)N_EDGES * 4);
    int*   col    = (int*)  alloc(COL_CAP * 4);
    int*   bsum   = (int*)  alloc((size_t)NB_SCAN * 4);
    int*   bo     = (int*)  alloc((size_t)NB_SCAN * 4);
    short* W1b    = (short*)alloc((size_t)DHID * DIN * 2);
    short* Wctb   = (short*)alloc((size_t)2 * DOUT * DHID * 2);
    short* xb     = (short*)alloc((size_t)N_NODES * DIN * 2);
    short* u1b    = (short*)alloc((size_t)(N_NODES + 1) * DHID * 2);  // +sentinel row
    short* u2b    = (short*)alloc((size_t)(N_NODES + 1) * DHID * 2);
    short* a2b    = u1b;   // u1b dead after pull1; reuse

    hipMemsetAsync(cnt, 0, (size_t)N_NODES * 4, stream);
    hipMemsetAsync(u1b + (size_t)N_NODES * DHID, 0, DHID * 2, stream);  // zero sentinel
    hipMemsetAsync(u2b + (size_t)N_NODES * DHID, 0, DHID * 2, stream);
    wprep_kernel<<<192, 256, 0, stream>>>(W1, Wmu, Wlv, W1b, Wctb);
    count_kernel<<<1024, 256, 0, stream>>>(ei, cnt, loc);
    bsum_kernel<<<NB_SCAN, 1024, 0, stream>>>(cnt, bsum);
    bscan_kernel<<<1, 64, 0, stream>>>(bsum, bo, rowptr);
    scan_apply_kernel<<<NB_SCAN, 1024, 0, stream>>>(cnt, bo, rowptr, dis, col);
    fill_kernel<<<1024, 256, 0, stream>>>(ei, loc, rowptr, col);
    xprep_kernel<<<2048, 256, 0, stream>>>(x, dis, xb);
    gemm1_mfma_kernel<<<(N_NODES + 31) / 32, 256, 0, stream>>>(xb, W1b, u1b);
    pull_kernel<true><<<N_NODES / 4, 256, 0, stream>>>(rowptr, col, u1b, dis, b1,
                                                       (unsigned*)u2b);
    pull_kernel<false><<<N_NODES / 4, 256, 0, stream>>>(rowptr, col, u2b, dis, nullptr,
                                                        (unsigned*)a2b);
    gemm2_mfma_kernel<<<(N_NODES + 63) / 64, 256, 0, stream>>>(a2b, Wctb, bmu, blv, out);
}

// Round 8
// 281.830 us; speedup vs baseline: 1.0076x; 1.0076x over previous
//
#include <hip/hip_runtime.h>

#define N_NODES 50000
#define N_EDGES 800000
#define DIN 256
#define DHID 128
#define DOUT 64
#define NB_SCAN 49   // ceil(50000/1024)
#define SENT N_NODES // sentinel node with zero feature row

typedef __attribute__((ext_vector_type(8))) short short8;
typedef __attribute__((ext_vector_type(4))) float f32x4;

static __device__ __forceinline__ short f2bf(float f) {
    union { float f; unsigned u; } v; v.f = f;
    unsigned r = v.u + 0x7FFFu + ((v.u >> 16) & 1u);   // RNE
    return (short)(r >> 16);
}
static __device__ __forceinline__ float bflo(unsigned p) {
    union { unsigned u; float f; } v; v.u = p << 16; return v.f;
}
static __device__ __forceinline__ float bfhi(unsigned p) {
    union { unsigned u; float f; } v; v.u = p & 0xFFFF0000u; return v.f;
}

// ---------------- CSR build (rows padded to multiple of 16 with SENT) ----------------

__global__ void count_kernel(const int* __restrict__ ei, int* __restrict__ cnt,
                             int* __restrict__ loc) {
    int stride = gridDim.x * blockDim.x;
    for (int e = blockIdx.x * blockDim.x + threadIdx.x; e < N_EDGES; e += stride) {
        loc[e] = atomicAdd(&cnt[ei[N_EDGES + e]], 1);
    }
}

__global__ __launch_bounds__(1024) void bsum_kernel(const int* __restrict__ cnt,
                                                    int* __restrict__ bsum) {
    __shared__ int ws[16];
    int tid = threadIdx.x, i = blockIdx.x * 1024 + tid;
    int v = (i < N_NODES) ? cnt[i] : 0;
    v = (v + 15) & ~15;   // padded length
    #pragma unroll
    for (int off = 32; off >= 1; off >>= 1) v += __shfl_xor(v, off);
    if ((tid & 63) == 0) ws[tid >> 6] = v;
    __syncthreads();
    if (tid == 0) {
        int s = 0;
        #pragma unroll
        for (int w = 0; w < 16; ++w) s += ws[w];
        bsum[blockIdx.x] = s;
    }
}

__global__ void bscan_kernel(const int* __restrict__ bsum, int* __restrict__ bo,
                             int* __restrict__ rowptr) {
    int l = threadIdx.x;   // 64 threads
    int v = (l < NB_SCAN) ? bsum[l] : 0;
    int x = v;
    #pragma unroll
    for (int off = 1; off < 64; off <<= 1) {
        int y = __shfl_up(x, off);
        if (l >= off) x += y;
    }
    if (l < NB_SCAN) bo[l] = x - v;
    if (l == 63) rowptr[N_NODES] = x;
}

__global__ __launch_bounds__(1024) void scan_apply_kernel(const int* __restrict__ cnt,
        const int* __restrict__ bo, int* __restrict__ rowptr,
        float* __restrict__ dis, int* __restrict__ col) {
    __shared__ int wsum[16];
    int tid = threadIdx.x, i = blockIdx.x * 1024 + tid;
    int lane = tid & 63, wid = tid >> 6;
    int v = (i < N_NODES) ? cnt[i] : 0;
    int p = (v + 15) & ~15;
    int x = p;
    #pragma unroll
    for (int off = 1; off < 64; off <<= 1) {
        int y = __shfl_up(x, off);
        if (lane >= off) x += y;
    }
    if (lane == 63) wsum[wid] = x;
    __syncthreads();
    if (tid == 0) {
        int s = 0;
        #pragma unroll
        for (int w = 0; w < 16; ++w) { int t = wsum[w]; wsum[w] = s; s += t; }
    }
    __syncthreads();
    int excl = bo[blockIdx.x] + wsum[wid] + (x - p);
    if (i < N_NODES) {
        rowptr[i] = excl;
        dis[i] = rsqrtf((float)(v + 1));
        for (int q = v; q < p; ++q) col[excl + q] = SENT;   // pad slots -> zero row
    }
}

// Atomic-free placement.
__global__ void fill_kernel(const int* __restrict__ ei, const int* __restrict__ loc,
                            const int* __restrict__ rowptr, int* __restrict__ col) {
    int stride = gridDim.x * blockDim.x;
    for (int e = blockIdx.x * blockDim.x + threadIdx.x; e < N_EDGES; e += stride) {
        int s = ei[e];
        int d = ei[N_EDGES + e];
        col[rowptr[d] + loc[e]] = s;
    }
}

// ---------------- weight prep (+ sentinel-row zeroing; grid = 193 blocks) ----------------

__global__ void wprep_kernel(const float* __restrict__ W1, const float* __restrict__ Wmu,
                             const float* __restrict__ Wlv, short* __restrict__ W1b,
                             short* __restrict__ Wctb, short* __restrict__ u1b,
                             short* __restrict__ u2b) {
    int tid = blockIdx.x * blockDim.x + threadIdx.x;
    if (tid < DHID * DIN) {
        W1b[tid] = f2bf(W1[tid]);
    } else if (tid < DHID * DIN + 2 * DOUT * DHID) {
        int t = tid - DHID * DIN;
        Wctb[t] = f2bf((t < DOUT * DHID) ? Wmu[t] : Wlv[t - DOUT * DHID]);
    } else if (tid < DHID * DIN + 2 * DOUT * DHID + DHID) {
        int t = tid - (DHID * DIN + 2 * DOUT * DHID);
        u1b[(size_t)SENT * DHID + t] = 0;   // zero sentinel rows
        u2b[(size_t)SENT * DHID + t] = 0;
    }
}

// ---------------- xprep: xb[n][k] = bf16(dis[n] * x[n][k]) ----------------

__global__ __launch_bounds__(256) void xprep_kernel(const float* __restrict__ x,
        const float* __restrict__ dis, short* __restrict__ xb) {
    const int total = N_NODES * (DIN / 8);
    int stride = gridDim.x * blockDim.x;
    for (int c = blockIdx.x * blockDim.x + threadIdx.x; c < total; c += stride) {
        int row = c >> 5;            // DIN/8 = 32 chunks per row
        float d = dis[row];
        const float* src = x + (size_t)c * 8;
        float4 f0 = *(const float4*)src;
        float4 f1 = *(const float4*)(src + 4);
        short8 o;
        o[0] = f2bf(f0.x * d); o[1] = f2bf(f0.y * d);
        o[2] = f2bf(f0.z * d); o[3] = f2bf(f0.w * d);
        o[4] = f2bf(f1.x * d); o[5] = f2bf(f1.y * d);
        o[6] = f2bf(f1.z * d); o[7] = f2bf(f1.w * d);
        *(short8*)(xb + (size_t)c * 8) = o;
    }
}

// ---------------- GEMM1 (MFMA bf16): u1b = bf16(xb @ W1^T) ----------------
// gemm2-proven wave shape: 16 rows x 128 cols (8 c-frags)/wave, 4 waves = 64 rows.
// Per ks-step: 1 A-load + 8 independent B-loads feed 8 MFMAs directly.

__global__ __launch_bounds__(256) void gemm1_mfma_kernel(const short* __restrict__ xb,
        const short* __restrict__ W1b, short* __restrict__ u1b) {
    const int lane = threadIdx.x & 63, w = threadIdx.x >> 6;
    const int l15 = lane & 15, kg = lane >> 4;
    const int nb = blockIdx.x * 64;
    const int r0 = nb + w * 16 + l15;
    const bool valid = r0 < N_NODES;
    const short* arow = xb + (size_t)r0 * DIN;

    f32x4 acc[8] = {};
    #pragma unroll
    for (int ks = 0; ks < 8; ++ks) {
        const int k0 = ks * 32 + kg * 8;
        short8 a = valid ? *(const short8*)(arow + k0)
                         : short8{0, 0, 0, 0, 0, 0, 0, 0};
        #pragma unroll
        for (int c = 0; c < 8; ++c) {
            short8 b = *(const short8*)(W1b + (size_t)(c * 16 + l15) * DIN + k0);
            acc[c] = __builtin_amdgcn_mfma_f32_16x16x32_bf16(a, b, acc[c], 0, 0, 0);
        }
    }

    const int rb = nb + w * 16 + kg * 4;
    #pragma unroll
    for (int c = 0; c < 8; ++c) {
        const int j = c * 16 + l15;
        #pragma unroll
        for (int e = 0; e < 4; ++e) {
            int r = rb + e;
            if (r < N_NODES)
                u1b[(size_t)r * DHID + j] = f2bf(acc[c][e]);
        }
    }
}

// ---------------- pull aggregation (one wave per node; padded rows, x16 gathers) ----------------

template <bool LAYER1>
__global__ __launch_bounds__(256) void pull_kernel(const int* __restrict__ rowptr,
        const int* __restrict__ col, const short* __restrict__ uin,
        const float* __restrict__ dis, const float* __restrict__ b1,
        unsigned* __restrict__ uout) {
    const int wid = threadIdx.x >> 6, lane = threadIdx.x & 63;
    const int i = blockIdx.x * 4 + wid;
    if (i >= N_NODES) return;
    const int beg = rowptr[i], end = rowptr[i + 1];
    const unsigned* __restrict__ up = (const unsigned*)uin;   // row stride 64 dwords
    float ax = 0.f, ay = 0.f;
    for (int base = beg; base < end; base += 64) {
        const int rem = end - base;
        const int m = rem < 64 ? rem : 64;          // multiple of 16
        int cv = (lane < m) ? col[base + lane] : SENT;
        for (int t = 0; t < m; t += 16) {
            int c0 = __shfl(cv, t);
            int c1 = __shfl(cv, t + 1);
            int c2 = __shfl(cv, t + 2);
            int c3 = __shfl(cv, t + 3);
            int c4 = __shfl(cv, t + 4);
            int c5 = __shfl(cv, t + 5);
            int c6 = __shfl(cv, t + 6);
            int c7 = __shfl(cv, t + 7);
            int c8 = __shfl(cv, t + 8);
            int c9 = __shfl(cv, t + 9);
            int ca = __shfl(cv, t + 10);
            int cb = __shfl(cv, t + 11);
            int cc = __shfl(cv, t + 12);
            int cd = __shfl(cv, t + 13);
            int ce = __shfl(cv, t + 14);
            int cf = __shfl(cv, t + 15);
            unsigned v0 = up[(size_t)c0 * 64 + lane];
            unsigned v1 = up[(size_t)c1 * 64 + lane];
            unsigned v2 = up[(size_t)c2 * 64 + lane];
            unsigned v3 = up[(size_t)c3 * 64 + lane];
            unsigned v4 = up[(size_t)c4 * 64 + lane];
            unsigned v5 = up[(size_t)c5 * 64 + lane];
            unsigned v6 = up[(size_t)c6 * 64 + lane];
            unsigned v7 = up[(size_t)c7 * 64 + lane];
            unsigned v8 = up[(size_t)c8 * 64 + lane];
            unsigned v9 = up[(size_t)c9 * 64 + lane];
            unsigned va = up[(size_t)ca * 64 + lane];
            unsigned vb = up[(size_t)cb * 64 + lane];
            unsigned vc = up[(size_t)cc * 64 + lane];
            unsigned vd = up[(size_t)cd * 64 + lane];
            unsigned ve = up[(size_t)ce * 64 + lane];
            unsigned vf = up[(size_t)cf * 64 + lane];
            ax += bflo(v0); ay += bfhi(v0);
            ax += bflo(v1); ay += bfhi(v1);
            ax += bflo(v2); ay += bfhi(v2);
            ax += bflo(v3); ay += bfhi(v3);
            ax += bflo(v4); ay += bfhi(v4);
            ax += bflo(v5); ay += bfhi(v5);
            ax += bflo(v6); ay += bfhi(v6);
            ax += bflo(v7); ay += bfhi(v7);
            ax += bflo(v8); ay += bfhi(v8);
            ax += bflo(v9); ay += bfhi(v9);
            ax += bflo(va); ay += bfhi(va);
            ax += bflo(vb); ay += bfhi(vb);
            ax += bflo(vc); ay += bfhi(vc);
            ax += bflo(vd); ay += bfhi(vd);
            ax += bflo(ve); ay += bfhi(ve);
            ax += bflo(vf); ay += bfhi(vf);
        }
    }
    const float di = dis[i];
    const unsigned sv = up[(size_t)i * 64 + lane];
    float tx = di * (ax + bflo(sv));
    float ty = di * (ay + bfhi(sv));
    if (LAYER1) {
        float2 b = *(const float2*)(b1 + lane * 2);
        tx = fmaxf(tx + b.x, 0.f) * di;
        ty = fmaxf(ty + b.y, 0.f) * di;
    }
    unsigned o = ((unsigned)(unsigned short)f2bf(tx)) |
                 (((unsigned)(unsigned short)f2bf(ty)) << 16);
    uout[(size_t)i * 64 + lane] = o;
}

// ---------------- GEMM2 (MFMA bf16): [mu|lv] = a2b @ Wctb^T + [bmu|blv] ----------------

__global__ __launch_bounds__(256) void gemm2_mfma_kernel(const short* __restrict__ a2b,
        const short* __restrict__ Wctb, const float* __restrict__ bmu,
        const float* __restrict__ blv, float* __restrict__ out) {
    const int lane = threadIdx.x & 63, w = threadIdx.x >> 6;
    const int l15 = lane & 15, kg = lane >> 4;
    const int nb = blockIdx.x * 64;
    const int r0 = nb + w * 16 + l15;
    const bool valid = r0 < N_NODES;
    const short* arow = a2b + (size_t)r0 * DHID;

    f32x4 acc[8] = {};
    #pragma unroll
    for (int ks = 0; ks < 4; ++ks) {
        const int k0 = ks * 32 + kg * 8;
        short8 a = valid ? *(const short8*)(arow + k0)
                         : short8{0, 0, 0, 0, 0, 0, 0, 0};
        #pragma unroll
        for (int c = 0; c < 8; ++c) {
            short8 b = *(const short8*)(Wctb + (size_t)(c * 16 + l15) * DHID + k0);
            acc[c] = __builtin_amdgcn_mfma_f32_16x16x32_bf16(a, b, acc[c], 0, 0, 0);
        }
    }

    float bias[8];
    #pragma unroll
    for (int c = 0; c < 8; ++c) {
        int j = c * 16 + l15;
        bias[c] = (j < DOUT) ? bmu[j] : blv[j - DOUT];
    }
    const int rb = nb + w * 16 + kg * 4;
    #pragma unroll
    for (int c = 0; c < 8; ++c) {
        const int j = c * 16 + l15;
        float* dst = (j < DOUT) ? (out + j)
                                : (out + (size_t)N_NODES * DOUT + (j - DOUT));
        #pragma unroll
        for (int e = 0; e < 4; ++e) {
            int r = rb + e;
            if (r < N_NODES)
                dst[(size_t)r * DOUT] = acc[c][e] + bias[c];
        }
    }
}

// ---------------- launcher ----------------

extern "C" void kernel_launch(void* const* d_in, const int* in_sizes, int n_in,
                              void* d_out, int out_size, void* d_ws, size_t ws_size,
                              hipStream_t stream) {
    const float* x   = (const float*)d_in[0];
    const int*   ei  = (const int*)d_in[1];
    const float* W1  = (const float*)d_in[2];
    const float* b1  = (const float*)d_in[3];
    const float* Wmu = (const float*)d_in[4];
    const float* bmu = (const float*)d_in[5];
    const float* Wlv = (const float*)d_in[6];
    const float* blv = (const float*)d_in[7];
    float* out = (float*)d_out;

    char* ws = (char*)d_ws;
    size_t off = 0;
    auto alloc = [&](size_t bytes) -> char* {
        char* p = ws + off;
        off += (bytes + 255) & ~(size_t)255;
        return p;
    };
    const size_t COL_CAP = (size_t)N_EDGES + 16 * (size_t)N_NODES + 64;  // padded CSR
    int*   cnt    = (int*)  alloc((size_t)N_NODES * 4);
    int*   rowptr = (int*)  alloc((size_t)(N_NODES + 1) * 4);
    float* dis    = (float*)alloc((size_t)N_NODES * 4);
    int*   loc    = (int*)  alloc((size_t)N_EDGES * 4);
    int*   col    = (int*)  alloc(COL_CAP * 4);
    int*   bsum   = (int*)  alloc((size_t)NB_SCAN * 4);
    int*   bo     = (int*)  alloc((size_t)NB_SCAN * 4);
    short* W1b    = (short*)alloc((size_t)DHID * DIN * 2);
    short* Wctb   = (short*)alloc((size_t)2 * DOUT * DHID * 2);
    short* xb     = (short*)alloc((size_t)N_NODES * DIN * 2);
    short* u1b    = (short*)alloc((size_t)(N_NODES + 1) * DHID * 2);  // +sentinel row
    short* u2b    = (short*)alloc((size_t)(N_NODES + 1) * DHID * 2);
    short* a2b    = u1b;   // u1b dead after pull1; reuse

    hipMemsetAsync(cnt, 0, (size_t)N_NODES * 4, stream);
    wprep_kernel<<<193, 256, 0, stream>>>(W1, Wmu, Wlv, W1b, Wctb, u1b, u2b);
    count_kernel<<<1024, 256, 0, stream>>>(ei, cnt, loc);
    bsum_kernel<<<NB_SCAN, 1024, 0, stream>>>(cnt, bsum);
    bscan_kernel<<<1, 64, 0, stream>>>(bsum, bo, rowptr);
    scan_apply_kernel<<<NB_SCAN, 1024, 0, stream>>>(cnt, bo, rowptr, dis, col);
    fill_kernel<<<1024, 256, 0, stream>>>(ei, loc, rowptr, col);
    xprep_kernel<<<2048, 256, 0, stream>>>(x, dis, xb);
    gemm1_mfma_kernel<<<(N_NODES + 63) / 64, 256, 0, stream>>>(xb, W1b, u1b);
    pull_kernel<true><<<N_NODES / 4, 256, 0, stream>>>(rowptr, col, u1b, dis, b1,
                                                       (unsigned*)u2b);
    pull_kernel<false><<<N_NODES / 4, 256, 0, stream>>>(rowptr, col, u2b, dis, nullptr,
                                                        (unsigned*)a2b);
    gemm2_mfma_kernel<<<(N_NODES + 63) / 64, 256, 0, stream>>>(a2b, Wctb, bmu, blv, out);
}